// Round 2
// baseline (279.647 us; speedup 1.0000x reference)
//
#include <hip/hip_runtime.h>
#include <math.h>

#define KK 20
#define NPTS 8192
#define NQ_PER_BLOCK 32
#define NCHUNK 8            // lanes (chunks) per query
#define THREADS 256
#define HALF 4096           // points staged per pass (64KB as float4)
#define CHUNK_HALF 512      // per-lane candidates per pass

// Exact (non-contracted) IEEE ops to match the NumPy reference bit-for-bit.
// np.sum (pairwise base case, n<8) accumulates ASCENDING: (x^2 + y^2) + z^2.
__device__ __forceinline__ float norm3(float x, float y, float z) {
    return __fadd_rn(__fadd_rn(__fmul_rn(x, x), __fmul_rn(y, y)), __fmul_rn(z, z));
}

extern "C" __global__ __launch_bounds__(THREADS, 1)
void knn_kernel(const float* __restrict__ verts, int* __restrict__ out)
{
    // 64KB static LDS: pass 0/1 point staging; later reused for list merge.
    __shared__ unsigned char smem_raw[65536];
    float4* pts = (float4*)smem_raw;

    const int t = threadIdx.x;
    const int q = t >> 3;        // query slot within block: 0..31
    const int l = t & 7;         // chunk lane: 0..7
    const int qg = blockIdx.x * NQ_PER_BLOCK + q;

    // Query point (batch 0), norm recomputed with the exact same op order.
    const float qx = verts[qg * 3 + 0];
    const float qy = verts[qg * 3 + 1];
    const float qz = verts[qg * 3 + 2];
    const float qn = norm3(qx, qy, qz);

    // Sorted ascending top-K list (distance, index) in registers.
    float dl[KK];
    int   il[KK];
#pragma unroll
    for (int k = 0; k < KK; ++k) { dl[k] = INFINITY; il[k] = 0x7fffffff; }

    for (int pass = 0; pass < 2; ++pass) {
        __syncthreads();   // protect LDS reuse between passes
        // Stage HALF points as float4{x,y,z,norm}, XOR-swizzled for bank spread.
#pragma unroll
        for (int s = 0; s < HALF / THREADS; ++s) {
            const int m = s * THREADS + t;           // local 0..4095
            const int n = pass * HALF + m;           // global point id
            const float x = verts[n * 3 + 0];
            const float y = verts[n * 3 + 1];
            const float z = verts[n * 3 + 2];
            const float nn = norm3(x, y, z);
            pts[m ^ ((m >> 9) & 7)] = make_float4(x, y, z, nn);
        }
        __syncthreads();

        // Scan this lane's chunk: candidates n = pass*HALF + l*512 + j (ascending).
        const int nbase = pass * HALF + l * CHUNK_HALF;
        const int mbase = l * CHUNK_HALF;
        for (int j = 0; j < CHUNK_HALF; ++j) {
            const int m = mbase + j;
            const float4 p = pts[m ^ ((m >> 9) & 7)];
            // np.einsum (optimize=False) remainder switch falls through in
            // DESCENDING index order for count=3:
            //   accum = ((z*z') + y*y') + x*x'
            const float dot = __fadd_rn(
                __fadd_rn(__fmul_rn(p.z, qz), __fmul_rn(p.y, qy)),
                __fmul_rn(p.x, qx));
            // dist[n,m] = ((-2*dot) + norm_src[n]) + norm_dst[m], exact order.
            const float d = __fadd_rn(__fadd_rn(__fmul_rn(dot, -2.0f), p.w), qn);

            if (d < dl[KK - 1]) {           // strict < : stable (keep earlier idx on ties)
                const int n = nbase + j;
                bool b[KK];
#pragma unroll
                for (int k = 0; k < KK; ++k) b[k] = d < dl[k];
#pragma unroll
                for (int k = KK - 1; k >= 1; --k) {
                    il[k] = b[k - 1] ? il[k - 1] : (b[k] ? n : il[k]);
                    // sorted invariant => median(d, dl[k-1], dl[k]) is the new dl[k]
                    dl[k] = __builtin_amdgcn_fmed3f(d, dl[k - 1], dl[k]);
                }
                il[0] = b[0] ? n : il[0];
                dl[0] = fminf(d, dl[0]);
            }
        }
    }

    __syncthreads();
    // Dump per-lane sorted lists to LDS (reusing the points buffer).
    float* ld = (float*)smem_raw;                         // 256*20*4 = 20480 B
    int*   li = (int*)(smem_raw + THREADS * KK * 4);      // next 20480 B
#pragma unroll
    for (int k = 0; k < KK; ++k) { ld[t * KK + k] = dl[k]; li[t * KK + k] = il[k]; }
    __syncthreads();

    // 8-way merge per query by threads 0..31 (static-index tournament, 20 rounds).
    if (t < NQ_PER_BLOCK) {
        float hd[NCHUNK]; int hi[NCHUNK]; int hp[NCHUNK];
#pragma unroll
        for (int c = 0; c < NCHUNK; ++c) {
            const int tt = t * NCHUNK + c;
            hd[c] = ld[tt * KK];
            hi[c] = li[tt * KK];
            hp[c] = 0;
        }
        const int obase = (blockIdx.x * NQ_PER_BLOCK + t) * KK;
        for (int r = 0; r < KK; ++r) {
            // min by (d, idx) lexicographic — exact top_k tie-break.
            float bd = hd[0]; int bi = hi[0]; int bc = 0;
#pragma unroll
            for (int c = 1; c < NCHUNK; ++c) {
                const bool takec = (hd[c] < bd) || ((hd[c] == bd) && (hi[c] < bi));
                bd = takec ? hd[c] : bd;
                bi = takec ? hi[c] : bi;
                bc = takec ? c : bc;
            }
            out[obase + r] = bi;
            // advance the winning list's head (static indices, exec-masked)
#pragma unroll
            for (int c = 0; c < NCHUNK; ++c) {
                if (bc == c) {
                    hp[c]++;
                    const int tt = t * NCHUNK + c;
                    const bool ok = hp[c] < KK;
                    const int a = tt * KK + (ok ? hp[c] : 0);
                    hd[c] = ok ? ld[a] : INFINITY;
                    hi[c] = ok ? li[a] : 0x7fffffff;
                }
            }
        }
    }
}

extern "C" void kernel_launch(void* const* d_in, const int* in_sizes, int n_in,
                              void* d_out, int out_size, void* d_ws, size_t ws_size,
                              hipStream_t stream) {
    // d_in[0] = feats (unused). d_in[1] = vertices [4,8192,3] f32; batch 0 only.
    const float* verts = (const float*)d_in[1];
    int* out = (int*)d_out;
    knn_kernel<<<dim3(NPTS / NQ_PER_BLOCK), dim3(THREADS), 0, stream>>>(verts, out);
}

// Round 3
// 151.873 us; speedup vs baseline: 1.8413x; 1.8413x over previous
//
#include <hip/hip_runtime.h>
#include <math.h>

#define KK 20
#define NPTS 8192
#define NQB 16              // queries per block
#define NCH 16              // chunks (lanes) per query
#define THREADS 256
#define WIN 2048            // points per staged LDS window
#define NWIN (NPTS / WIN)   // 4
#define JPW (WIN / NCH)     // 128 candidates per lane per window
#define CAP 40              // hit buffer capacity per query

// Exact (non-contracted) IEEE ops matching the NumPy reference bit-for-bit.
// np.sum (pairwise, n<8) accumulates ascending: (x^2 + y^2) + z^2.
__device__ __forceinline__ float norm3(float x, float y, float z) {
    return __fadd_rn(__fadd_rn(__fmul_rn(x, x), __fmul_rn(y, y)), __fmul_rn(z, z));
}

// np.einsum (optimize=False) remainder switch falls through DESCENDING for
// count=3: ((z*z') + y*y') + x*x'.  dist = ((-2*dot) + n_src) + n_dst.
__device__ __forceinline__ float distf(const float4& p, float qx, float qy,
                                       float qz, float qn) {
    const float dot = __fadd_rn(
        __fadd_rn(__fmul_rn(p.z, qz), __fmul_rn(p.y, qy)), __fmul_rn(p.x, qx));
    return __fadd_rn(__fadd_rn(__fmul_rn(dot, -2.0f), p.w), qn);
}

extern "C" __global__ __launch_bounds__(THREADS, 2)
void knn_kernel(const float* __restrict__ verts, int* __restrict__ out)
{
    __shared__ float4 pts[WIN];             // 32 KiB, XOR-swizzled slots
    __shared__ float  ldump[THREADS][KK];   // 20 KiB value lists
    __shared__ float  Tq[NQB];
    __shared__ int    cnt[NQB];
    __shared__ float  hbd[NQB][CAP];        // hit distances
    __shared__ int    hbi[NQB][CAP];        // hit indices

    const int t = threadIdx.x;
    const int q = t & (NQB - 1);            // query slot 0..15
    const int c = t >> 4;                   // chunk 0..15
    const int qg = blockIdx.x * NQB + q;

    const float qx = verts[qg * 3 + 0];
    const float qy = verts[qg * 3 + 1];
    const float qz = verts[qg * 3 + 2];
    const float qn = norm3(qx, qy, qz);

    const int mbase = c * JPW;
    const int xr = c & 7;                   // per-chunk bank-spread XOR

    // ---------------- PASS 1: values-only per-lane top-20 ----------------
    float dl[KK];
#pragma unroll
    for (int k = 0; k < KK; ++k) dl[k] = INFINITY;

    for (int s = 0; s < NWIN; ++s) {
        __syncthreads();
        // Stage window s: strided m => conflict-free LDS writes, coalesced reads.
#pragma unroll
        for (int i = 0; i < WIN / THREADS; ++i) {
            const int m = i * THREADS + t;
            const int n = s * WIN + m;
            const float x = verts[n * 3 + 0];
            const float y = verts[n * 3 + 1];
            const float z = verts[n * 3 + 2];
            pts[m ^ ((m >> 7) & 7)] = make_float4(x, y, z, norm3(x, y, z));
        }
        __syncthreads();
#pragma unroll 4
        for (int j = 0; j < JPW; ++j) {
            const float4 p = pts[mbase + (j ^ xr)];   // 16-lane broadcast, 4 banks/wave
            const float d = distf(p, qx, qy, qz, qn);
            // Unconditional sorted-insert of the VALUE only: 20 independent ops.
#pragma unroll
            for (int k = KK - 1; k >= 1; --k)
                dl[k] = __builtin_amdgcn_fmed3f(d, dl[k - 1], dl[k]);
            dl[0] = fminf(d, dl[0]);
        }
    }

    // ---------------- Merge per query: exact 20th-smallest value T --------
    __syncthreads();
#pragma unroll
    for (int k = 0; k < KK; ++k) ldump[t][k] = dl[k];
    for (int i = t; i < NQB * CAP; i += THREADS) {
        (&hbd[0][0])[i] = INFINITY;
        (&hbi[0][0])[i] = 0x7fffffff;
    }
    if (t < NQB) cnt[t] = 0;
    __syncthreads();

    if (t < NQB) {
        float hd16[NCH]; int hp16[NCH];
#pragma unroll
        for (int cc = 0; cc < NCH; ++cc) {
            hd16[cc] = ldump[cc * NQB + t][0];
            hp16[cc] = 0;
        }
        float T = INFINITY;
        for (int r = 0; r < KK; ++r) {
            float bd = hd16[0]; int bc = 0;
#pragma unroll
            for (int cc = 1; cc < NCH; ++cc) {
                const bool takec = hd16[cc] < bd;
                bd = takec ? hd16[cc] : bd;
                bc = takec ? cc : bc;
            }
            T = bd;
#pragma unroll
            for (int cc = 0; cc < NCH; ++cc) {
                if (bc == cc) {
                    hp16[cc]++;
                    const bool ok = hp16[cc] < KK;
                    hd16[cc] = ok ? ldump[cc * NQB + t][hp16[cc]] : INFINITY;
                }
            }
        }
        Tq[t] = T;
    }
    __syncthreads();
    const float T = Tq[q];

    // ---------------- PASS 2: rescan, collect all (d <= T) ----------------
    // Window NWIN-1 is still resident in pts from pass 1 -> scan it first.
    for (int si = 0; si < NWIN; ++si) {
        const int s = (si == 0) ? (NWIN - 1) : (si - 1);
        if (si != 0) {
            __syncthreads();
#pragma unroll
            for (int i = 0; i < WIN / THREADS; ++i) {
                const int m = i * THREADS + t;
                const int n = s * WIN + m;
                const float x = verts[n * 3 + 0];
                const float y = verts[n * 3 + 1];
                const float z = verts[n * 3 + 2];
                pts[m ^ ((m >> 7) & 7)] = make_float4(x, y, z, norm3(x, y, z));
            }
            __syncthreads();
        }
#pragma unroll 4
        for (int j = 0; j < JPW; ++j) {
            const float4 p = pts[mbase + (j ^ xr)];
            const float d = distf(p, qx, qy, qz, qn);
            if (d <= T) {                         // ~20 hits per query total
                const int n = s * WIN + mbase + j;
                const int slot = atomicAdd(&cnt[q], 1);
                if (slot < CAP) { hbd[q][slot] = d; hbi[q][slot] = n; }
            }
        }
    }
    __syncthreads();

    // ---------------- Final: 20 smallest by (d, idx) lex per query --------
    if (t < NQB) {
        const int kc = min(cnt[t], CAP);
        const int obase = (blockIdx.x * NQB + t) * KK;
        for (int r = 0; r < KK; ++r) {
            float bd = INFINITY; int bi = 0x7fffffff; int bj = -1;
            for (int e = 0; e < kc; ++e) {
                const float ed = hbd[t][e]; const int ei = hbi[t][e];
                const bool takee = (ed < bd) || ((ed == bd) && (ei < bi));
                bd = takee ? ed : bd;
                bi = takee ? ei : bi;
                bj = takee ? e : bj;
            }
            out[obase + r] = bi;
            if (bj >= 0) { hbd[t][bj] = INFINITY; hbi[t][bj] = 0x7fffffff; }
        }
    }
}

extern "C" void kernel_launch(void* const* d_in, const int* in_sizes, int n_in,
                              void* d_out, int out_size, void* d_ws, size_t ws_size,
                              hipStream_t stream) {
    // d_in[0] = feats (unused). d_in[1] = vertices [4,8192,3] f32; batch 0 only.
    const float* verts = (const float*)d_in[1];
    int* out = (int*)d_out;
    knn_kernel<<<dim3(NPTS / NQB), dim3(THREADS), 0, stream>>>(verts, out);
}

// Round 4
// 56.914 us; speedup vs baseline: 4.9135x; 2.6684x over previous
//
#include <hip/hip_runtime.h>
#include <math.h>

#define KK 20
#define NPTS 8192
#define NQB 16              // queries per block
#define NCH 128             // chunk-lanes per query
#define THREADS 256
#define WIN 2048            // points per staged LDS window
#define NWIN (NPTS / WIN)   // 4
#define JPW (WIN / NCH)     // 16 candidates per lane per window
#define QPL 8               // queries register-tiled per lane
#define CAP 64              // hit buffer capacity per query

// Exact (non-contracted) IEEE ops matching the NumPy reference bit-for-bit.
// np.sum (pairwise, n<8) accumulates ascending: (x^2 + y^2) + z^2.
__device__ __forceinline__ float norm3(float x, float y, float z) {
    return __fadd_rn(__fadd_rn(__fmul_rn(x, x), __fmul_rn(y, y)), __fmul_rn(z, z));
}

// np.einsum (optimize=False) remainder falls through DESCENDING for count=3:
// ((z*z') + y*y') + x*x'.  dist = ((-2*dot) + n_src) + n_dst.
__device__ __forceinline__ float distf(float px, float py, float pz, float pw,
                                       float qx, float qy, float qz, float qn) {
    const float dot = __fadd_rn(
        __fadd_rn(__fmul_rn(pz, qz), __fmul_rn(py, qy)), __fmul_rn(px, qx));
    return __fadd_rn(__fadd_rn(__fmul_rn(dot, -2.0f), pw), qn);
}

extern "C" __global__ __launch_bounds__(THREADS, 2)
void knn_kernel(const float* __restrict__ verts, int* __restrict__ out)
{
    __shared__ float4 pts[WIN];                 // 32 KiB, slot-swizzled
    __shared__ float  vdump[NCH][NQB + 1];      // per-(chunk,query) minima, padded
    __shared__ float  Tq[NQB];
    __shared__ int    cnt[NQB];
    __shared__ float  hbd[NQB][CAP];
    __shared__ int    hbi[NQB][CAP];

    const int t    = threadIdx.x;
    const int lane = t & 63;
    const int wv   = t >> 6;        // wave id 0..3
    const int c    = t >> 1;        // chunk 0..127
    const int qh   = t & 1;         // query half (0: q0..7, 1: q8..15)
    const int xr   = c & 7;         // bank-spread XOR for this chunk
    const int qbase = blockIdx.x * NQB + qh * QPL;

    // Register tile: 8 queries per lane (exact same norm op-order as reference).
    float qx[QPL], qy[QPL], qz[QPL], qn[QPL];
#pragma unroll
    for (int i = 0; i < QPL; ++i) {
        qx[i] = verts[(qbase + i) * 3 + 0];
        qy[i] = verts[(qbase + i) * 3 + 1];
        qz[i] = verts[(qbase + i) * 3 + 2];
        qn[i] = norm3(qx[i], qy[i], qz[i]);
    }

    // ---------------- PASS 1: per-(lane,query) MIN distance only ----------
    float mn[QPL];
#pragma unroll
    for (int i = 0; i < QPL; ++i) mn[i] = INFINITY;

    for (int w = 0; w < NWIN; ++w) {
        __syncthreads();
#pragma unroll
        for (int i = 0; i < WIN / THREADS; ++i) {   // stage window w
            const int m = i * THREADS + t;
            const int n = w * WIN + m;
            const float x = verts[n * 3 + 0];
            const float y = verts[n * 3 + 1];
            const float z = verts[n * 3 + 2];
            pts[m ^ ((m >> 4) & 7)] = make_float4(x, y, z, norm3(x, y, z));
        }
        __syncthreads();
#pragma unroll 4
        for (int v = 0; v < JPW; ++v) {
            // swizzled slot: lanes spread across bank-quads; logical id unneeded here
            const float4 p = pts[c * JPW + (v ^ xr)];
#pragma unroll
            for (int i = 0; i < QPL; ++i)
                mn[i] = fminf(mn[i], distf(p.x, p.y, p.z, p.w,
                                           qx[i], qy[i], qz[i], qn[i]));
        }
    }

    // ---------------- Merge: T' = 20th smallest of 128 lane-minima --------
#pragma unroll
    for (int i = 0; i < QPL; ++i) vdump[c][qh * QPL + i] = mn[i];
    if (t < NQB) cnt[t] = 0;
    __syncthreads();

    // wave wv computes T' for queries 4wv..4wv+3 via 128-elem bitonic (2 regs/lane)
    for (int qq = wv * 4; qq < wv * 4 + 4; ++qq) {
        float v0 = vdump[lane * 2 + 0][qq];
        float v1 = vdump[lane * 2 + 1][qq];
#pragma unroll
        for (int k = 2; k <= 128; k <<= 1) {
#pragma unroll
            for (int j = k >> 1; j >= 1; j >>= 1) {
                const bool asc = ((lane & (k >> 1)) == 0);
                if (j == 1) {       // in-register exchange (elements 2L, 2L+1)
                    const float lo = fminf(v0, v1), hi = fmaxf(v0, v1);
                    v0 = asc ? lo : hi;
                    v1 = asc ? hi : lo;
                } else {
                    const int jj = j >> 1;
                    const float o0 = __shfl_xor(v0, jj);
                    const float o1 = __shfl_xor(v1, jj);
                    const bool lower = ((lane & jj) == 0);
                    const bool keepmin = (lower == asc);
                    v0 = keepmin ? fminf(v0, o0) : fmaxf(v0, o0);
                    v1 = keepmin ? fminf(v1, o1) : fmaxf(v1, o1);
                }
            }
        }
        const float T = __shfl(v1, 9);          // element 19 = lane 9, reg 1
        if (lane == 0) Tq[qq] = T;
    }
    __syncthreads();

    float Tl[QPL];
#pragma unroll
    for (int i = 0; i < QPL; ++i) Tl[i] = Tq[qh * QPL + i];

    // ---------------- PASS 2: rescan, collect all (d <= T') ---------------
    // Window NWIN-1 is still resident -> scan it first, then restage 0,1,2.
    for (int ww = 0; ww < NWIN; ++ww) {
        const int w = (ww == 0) ? (NWIN - 1) : (ww - 1);
        if (ww != 0) {
            __syncthreads();
#pragma unroll
            for (int i = 0; i < WIN / THREADS; ++i) {
                const int m = i * THREADS + t;
                const int n = w * WIN + m;
                const float x = verts[n * 3 + 0];
                const float y = verts[n * 3 + 1];
                const float z = verts[n * 3 + 2];
                pts[m ^ ((m >> 4) & 7)] = make_float4(x, y, z, norm3(x, y, z));
            }
            __syncthreads();
        }
#pragma unroll 4
        for (int v = 0; v < JPW; ++v) {
            const float4 p = pts[c * JPW + (v ^ xr)];
            const int n = w * WIN + c * JPW + v;    // logical id of this slot
#pragma unroll
            for (int i = 0; i < QPL; ++i) {
                const float d = distf(p.x, p.y, p.z, p.w,
                                      qx[i], qy[i], qz[i], qn[i]);
                if (d <= Tl[i]) {
                    const int q = qh * QPL + i;
                    const int slot = atomicAdd(&cnt[q], 1);
                    if (slot < CAP) { hbd[q][slot] = d; hbi[q][slot] = n; }
                }
            }
        }
    }
    __syncthreads();

    // ---------------- Final: exact stable top-20 via u64 bitonic ----------
    for (int qq = wv * 4; qq < wv * 4 + 4; ++qq) {
        const int kc = min(cnt[qq], CAP);
        unsigned long long key = ~0ULL;
        if (lane < kc) {
            const float d = hbd[qq][lane];
            unsigned u = __float_as_uint(d);
            u ^= ((unsigned)((int)u >> 31)) | 0x80000000u;   // order-preserving map
            key = ((unsigned long long)u << 32) | (unsigned)hbi[qq][lane];
        }
#pragma unroll
        for (int k = 2; k <= 64; k <<= 1) {
#pragma unroll
            for (int j = k >> 1; j >= 1; j >>= 1) {
                const unsigned long long o = __shfl_xor(key, j);
                const bool asc = ((lane & k) == 0);
                const bool lower = ((lane & j) == 0);
                const bool keepmin = (lower == asc);
                const bool lt = key < o;
                key = (keepmin == lt) ? key : o;
            }
        }
        if (lane < KK)
            out[(blockIdx.x * NQB + qq) * KK + lane] =
                (int)(unsigned)(key & 0xffffffffULL);
    }
}

extern "C" void kernel_launch(void* const* d_in, const int* in_sizes, int n_in,
                              void* d_out, int out_size, void* d_ws, size_t ws_size,
                              hipStream_t stream) {
    // d_in[0] = feats (unused). d_in[1] = vertices [4,8192,3] f32; batch 0 only.
    const float* verts = (const float*)d_in[1];
    int* out = (int*)d_out;
    knn_kernel<<<dim3(NPTS / NQB), dim3(THREADS), 0, stream>>>(verts, out);
}

// Round 6
// 42.348 us; speedup vs baseline: 6.6035x; 1.3440x over previous
//
#include <hip/hip_runtime.h>
#include <math.h>

#define KK 20
#define NPTS 8192
#define NQB 16              // queries per block
#define QPL 4               // queries per lane
#define NGRP 4              // query groups per block = NQB/QPL
#define NCH 128             // chunks per query
#define THREADS 512
#define WIN 2048            // points per staged LDS window
#define NWIN 4
#define JPW (WIN / NCH)     // 16 candidates per chunk per window
#define PPT (WIN / THREADS) // 4 points staged per thread
#define CAP 64              // hit buffer capacity per query

// Exact (non-contracted) IEEE ops matching the NumPy reference bit-for-bit.
// np.sum (pairwise, n<8) accumulates ascending: (x^2 + y^2) + z^2.
__device__ __forceinline__ float norm3(float x, float y, float z) {
    return __fadd_rn(__fadd_rn(__fmul_rn(x, x), __fmul_rn(y, y)), __fmul_rn(z, z));
}

// np.einsum (optimize=False) remainder falls through DESCENDING for count=3:
// ((z*z') + y*y') + x*x'.  dist = ((-2*dot) + n_src) + n_dst.
__device__ __forceinline__ float distf(float px, float py, float pz, float pw,
                                       float qx, float qy, float qz, float qn) {
    const float dot = __fadd_rn(
        __fadd_rn(__fmul_rn(pz, qz), __fmul_rn(py, qy)), __fmul_rn(px, qx));
    return __fadd_rn(__fadd_rn(__fmul_rn(dot, -2.0f), pw), qn);
}

extern "C" __global__ __launch_bounds__(THREADS, 4)
void knn_kernel(const float* __restrict__ verts, int* __restrict__ out)
{
    // Static LDS, 49792 B total (<= 64 KiB: guaranteed-safe launch path).
    __shared__ float4 pts[WIN];                 // 32768 B
    __shared__ float  vdump[NCH][NQB + 1];      //  8704 B
    __shared__ float  hbd[NQB][CAP];            //  4096 B
    __shared__ int    hbi[NQB][CAP];            //  4096 B
    __shared__ float  Tq[NQB];
    __shared__ int    cnt[NQB];

    const int t    = threadIdx.x;
    const int lane = t & 63;
    const int wv   = t >> 6;          // wave 0..7
    const int c    = t >> 2;          // chunk 0..127
    const int qh   = t & 3;           // query group 0..3
    const int xr   = c & 15;          // read-order bank-spread XOR (bijective on 0..15)
    const int qbase = blockIdx.x * NQB + qh * QPL;

    if (t < NQB) cnt[t] = 0;

    // Register tile: 4 queries per lane, exact reference op-order norms.
    float qx[QPL], qy[QPL], qz[QPL], qn[QPL];
#pragma unroll
    for (int i = 0; i < QPL; ++i) {
        qx[i] = verts[(qbase + i) * 3 + 0];
        qy[i] = verts[(qbase + i) * 3 + 1];
        qz[i] = verts[(qbase + i) * 3 + 2];
        qn[i] = norm3(qx[i], qy[i], qz[i]);
    }

    // Staging registers (issue-early / write-late, T14).
    float sx[PPT], sy[PPT], sz[PPT];
    auto issue = [&](int w) {
#pragma unroll
        for (int i = 0; i < PPT; ++i) {
            const int n = w * WIN + i * THREADS + t;
            sx[i] = verts[n * 3 + 0];
            sy[i] = verts[n * 3 + 1];
            sz[i] = verts[n * 3 + 2];
        }
    };
    auto commit = [&]() {
#pragma unroll
        for (int i = 0; i < PPT; ++i) {
            const int m = i * THREADS + t;
            pts[m] = make_float4(sx[i], sy[i], sz[i], norm3(sx[i], sy[i], sz[i]));
        }
    };

    // ---------------- PASS 1: per-(chunk,query) MIN distance ----------------
    float mn[QPL];
#pragma unroll
    for (int i = 0; i < QPL; ++i) mn[i] = INFINITY;

    issue(0); commit(); __syncthreads();
#pragma unroll
    for (int w = 0; w < NWIN; ++w) {
        if (w + 1 < NWIN) issue(w + 1);        // prefetch next window (regs)
#pragma unroll 2
        for (int v = 0; v < JPW; ++v) {
            const float4 p = pts[c * JPW + (v ^ xr)];
#pragma unroll
            for (int i = 0; i < QPL; ++i)
                mn[i] = fminf(mn[i], distf(p.x, p.y, p.z, p.w,
                                           qx[i], qy[i], qz[i], qn[i]));
        }
        __syncthreads();                       // all reads of pts done
        if (w + 1 < NWIN) { commit(); __syncthreads(); }
        // after w == NWIN-1: window 3 stays resident for pass 2
    }

#pragma unroll
    for (int i = 0; i < QPL; ++i) vdump[c][qh * QPL + i] = mn[i];
    __syncthreads();

    // ---------------- T' = 20th smallest of 128 chunk-minima ----------------
    // Wave wv handles queries {2wv, 2wv+1}: 128-elem bitonic, 2 regs/lane.
#pragma unroll
    for (int r = 0; r < 2; ++r) {
        const int qq = wv * 2 + r;
        float v0 = vdump[lane * 2 + 0][qq];
        float v1 = vdump[lane * 2 + 1][qq];
#pragma unroll
        for (int k = 2; k <= 128; k <<= 1) {
#pragma unroll
            for (int j = k >> 1; j >= 1; j >>= 1) {
                const bool asc = ((lane & (k >> 1)) == 0);
                if (j == 1) {       // in-register exchange (elements 2L, 2L+1)
                    const float lo = fminf(v0, v1), hi = fmaxf(v0, v1);
                    v0 = asc ? lo : hi;
                    v1 = asc ? hi : lo;
                } else {
                    const int jj = j >> 1;
                    const float o0 = __shfl_xor(v0, jj);
                    const float o1 = __shfl_xor(v1, jj);
                    const bool lower = ((lane & jj) == 0);
                    const bool keepmin = (lower == asc);
                    v0 = keepmin ? fminf(v0, o0) : fmaxf(v0, o0);
                    v1 = keepmin ? fminf(v1, o1) : fmaxf(v1, o1);
                }
            }
        }
        const float T = __shfl(v1, 9);          // element 19 = lane 9, reg 1
        if (lane == 0) Tq[qq] = T;
    }
    __syncthreads();

    float Tl[QPL];
#pragma unroll
    for (int i = 0; i < QPL; ++i) Tl[i] = Tq[qh * QPL + i];

    // ---------------- PASS 2: rescan, collect all (d <= T') ----------------
    // Window 3 is still resident -> scan order {3,0,1,2}, prefetched.
#pragma unroll
    for (int ww = 0; ww < NWIN; ++ww) {
        const int w = (ww == 0) ? (NWIN - 1) : (ww - 1);
        if (ww + 1 < NWIN) issue(ww);          // next window in order == ww
#pragma unroll 2
        for (int v = 0; v < JPW; ++v) {
            const int mloc = c * JPW + (v ^ xr);
            const float4 p = pts[mloc];
            const int n = w * WIN + mloc;      // logical candidate id
#pragma unroll
            for (int i = 0; i < QPL; ++i) {
                const float d = distf(p.x, p.y, p.z, p.w,
                                      qx[i], qy[i], qz[i], qn[i]);
                if (d <= Tl[i]) {              // ~21 hits/query total
                    const int q = qh * QPL + i;
                    const int slot = atomicAdd(&cnt[q], 1);
                    if (slot < CAP) { hbd[q][slot] = d; hbi[q][slot] = n; }
                }
            }
        }
        __syncthreads();
        if (ww + 1 < NWIN) { commit(); __syncthreads(); }
    }

    // ---------------- Final: exact stable top-20 via u64 bitonic ------------
#pragma unroll
    for (int r = 0; r < 2; ++r) {
        const int qq = wv * 2 + r;
        const int kc = min(cnt[qq], CAP);      // kc >= 20 guaranteed
        unsigned long long key = ~0ULL;
        if (lane < kc) {
            const float d = hbd[qq][lane];
            unsigned u = __float_as_uint(d);
            u ^= ((unsigned)((int)u >> 31)) | 0x80000000u;   // order-preserving map
            key = ((unsigned long long)u << 32) | (unsigned)hbi[qq][lane];
        }
#pragma unroll
        for (int k = 2; k <= 64; k <<= 1) {
#pragma unroll
            for (int j = k >> 1; j >= 1; j >>= 1) {
                const unsigned long long o = __shfl_xor(key, j);
                const bool asc = ((lane & k) == 0);
                const bool lower = ((lane & j) == 0);
                const bool keepmin = (lower == asc);
                const bool lt = key < o;
                key = (keepmin == lt) ? key : o;
            }
        }
        if (lane < KK)
            out[(blockIdx.x * NQB + qq) * KK + lane] =
                (int)(unsigned)(key & 0xffffffffULL);
    }
}

extern "C" void kernel_launch(void* const* d_in, const int* in_sizes, int n_in,
                              void* d_out, int out_size, void* d_ws, size_t ws_size,
                              hipStream_t stream) {
    // d_in[0] = feats (unused). d_in[1] = vertices [4,8192,3] f32; batch 0 only.
    const float* verts = (const float*)d_in[1];
    int* out = (int*)d_out;
    knn_kernel<<<dim3(NPTS / NQB), dim3(THREADS), 0, stream>>>(verts, out);
}